// Round 5
// baseline (388.188 us; speedup 1.0000x reference)
//
#include <hip/hip_runtime.h>
#include <math.h>

// Problem constants (from reference): D=256, DIN=512, F=16
#define DD 256

// Workspace layout (float offsets). NO global atomics anywhere: blocks store
// private partials, tiny reducer kernels combine them.
#define OFF_PARTA  0            // [2][512][256] colsum partials      (262144)
#define OFF_PARTB  262144       // [2][512][256] att1 partials        (262144)
#define OFF_PARTO  524288       // [2][512][256] att2 (o) partials    (262144)
#define OFF_H1P    786432       // [2][256] pre-tanh h1
#define OFF_H2P    786944       // [2][256] pre-tanh h2
#define OFF_O      787456       // [2][256] final o
#define OFF_PWT    787968       // [512][16] ntn w_term partials      (8192)
#define MIRROR_OFF_BYTES 4194304   // fp16 mirror of x1,x2 starts at 4 MB

typedef float    f32x4 __attribute__((ext_vector_type(4)));
typedef float    f32x8 __attribute__((ext_vector_type(8)));
typedef _Float16 f16x4 __attribute__((ext_vector_type(4)));
typedef _Float16 f16x8 __attribute__((ext_vector_type(8)));

__device__ __forceinline__ float sigmoidf_(float x) { return 1.0f / (1.0f + __expf(-x)); }

// row-of-8 loaders: fp16 mirror (convert) or raw fp32 (fallback)
__device__ __forceinline__ f32x8 ld8(const f16x8* p, size_t i) {
    return __builtin_convertvector(p[i], f32x8);
}
__device__ __forceinline__ f32x8 ld8(const f32x8* p, size_t i) { return p[i]; }

__device__ __forceinline__ float dot8(f32x8 a, f32x8 b) {
    f32x8 m = a * b;
    return ((m[0] + m[4]) + (m[1] + m[5])) + ((m[2] + m[6]) + (m[3] + m[7]));
}

// f32x4 block reduce (4 waves) + PLAIN STORE of the block's 256-col partial.
__device__ __forceinline__ void block_reduce_store4(f32x4 acc, int t, float* dst) {
    __shared__ f32x4 lds[256];
    lds[t] = acc;
    __syncthreads();
    if (t < 64) {
        f32x4 s = lds[t] + lds[t + 64] + lds[t + 128] + lds[t + 192];
        ((f32x4*)dst)[t] = s;      // cols t*4..t*4+3
    }
}

// f32x8 block reduce (8 half-wave slots) + PLAIN STORE (att kernels).
__device__ __forceinline__ void block_reduce_store8(f32x8 acc, int t, float* dst) {
    __shared__ f32x8 lds8[256];
    lds8[t] = acc;
    __syncthreads();
    const float* lf = (const float*)lds8;
    float s = 0.f;
#pragma unroll
    for (int slot = 0; slot < 8; slot++) s += lf[slot * 256 + t];   // conflict-free
    dst[t] = s;
}

// Pass A: column sums (NT x loads: keep mirror L3-resident) + fp16 mirror write.
// Grid 1024: [0,512)->x1, [512,1024)->x2; wave-per-row, stride 2048 rows.
// Block bl stores its partial to PARTA[inp][bl][256].
template<bool WM>
__global__ void k_mean_t(const f32x4* __restrict__ x1, const f32x4* __restrict__ x2,
                         f16x4* __restrict__ m1, f16x4* __restrict__ m2,
                         int N1, int N2, float* __restrict__ ws) {
    int b = blockIdx.x, t = threadIdx.x;
    int inp = (b < 512) ? 0 : 1;
    int bl = inp ? (b - 512) : b;
    const f32x4* x = inp ? x2 : x1;
    f16x4* mm = inp ? m2 : m1;
    int N = inp ? N2 : N1;
    int col4 = t & 63, rg = t >> 6;
    f32x4 acc = {0.f, 0.f, 0.f, 0.f};
    for (int r = bl * 4 + rg; r < N; r += 2048) {
        size_t i0 = (size_t)r * 64 + col4;
        f32x4 v = __builtin_nontemporal_load(&x[i0]);   // NT: don't evict mirror
        if (WM) mm[i0] = __builtin_convertvector(v, f16x4);
        acc += v;
    }
    block_reduce_store4(acc, t, ws + OFF_PARTA + ((size_t)inp * 512 + bl) * 256);
}

// Reduce 512 partial slots -> colsum/N -> h_pre = (colsum/N) @ W0 (full matvec).
// Grid 2 (one block per input) x 1024 threads. Plain store, no atomics.
__global__ void k_h(const float* __restrict__ W0, float* __restrict__ ws,
                    int srcOff, int dstOff, int N1, int N2) {
    int inp = blockIdx.x, t = threadIdx.x;   // 1024 threads
    int col = t & 255, q = t >> 8;           // quarter q in [0,4)
    const float* src = ws + srcOff + (size_t)inp * 512 * 256;
    float s = 0.f;
#pragma unroll 4
    for (int k = q * 128; k < q * 128 + 128; k++) s += src[k * 256 + col];
    __shared__ float part[4][256];
    part[q][col] = s;
    __syncthreads();
    __shared__ float temp[256];
    if (t < 256) {
        float cs = part[0][t] + part[1][t] + part[2][t] + part[3][t];
        temp[t] = cs * (1.0f / (float)(inp ? N2 : N1));
    }
    __syncthreads();
    float p = 0.f;
#pragma unroll 4
    for (int j = q * 64; j < q * 64 + 64; j++) p += temp[j] * W0[j * 256 + col];
    part[q][col] = p;
    __syncthreads();
    if (t < 256)
        ws[dstOff + inp * 256 + t] = part[0][t] + part[1][t] + part[2][t] + part[3][t];
}

// Reduce PARTO -> o[2][256]. Grid 2 x 1024. Plain store.
__global__ void k_redo(float* __restrict__ ws) {
    int inp = blockIdx.x, t = threadIdx.x;
    int col = t & 255, q = t >> 8;
    const float* src = ws + OFF_PARTO + (size_t)inp * 512 * 256;
    float s = 0.f;
#pragma unroll 4
    for (int k = q * 128; k < q * 128 + 128; k++) s += src[k * 256 + col];
    __shared__ float part[4][256];
    part[q][col] = s;
    __syncthreads();
    if (t < 256)
        ws[OFF_O + inp * 256 + t] = part[0][t] + part[1][t] + part[2][t] + part[3][t];
}

// Pass B: s1 = sum_i sigmoid(x_i . h1) * x_i.
// 2 rows per wave (row = 32 lanes x 8 elems); grid 1024 (512/input), stride 4096 rows.
template<typename T>
__global__ void k_att1_t(const T* __restrict__ b1, const T* __restrict__ b2,
                         int N1, int N2, float* __restrict__ ws) {
    int b = blockIdx.x, t = threadIdx.x;
    int inp = (b < 512) ? 0 : 1;
    int bl = inp ? (b - 512) : b;
    const T* x = inp ? b2 : b1;
    int N = inp ? N2 : N1;
    int lane = t & 63, w = t >> 6;
    int half = lane >> 5, l32 = lane & 31;
    f32x8 h1;
#pragma unroll
    for (int j = 0; j < 8; j++) h1[j] = tanhf(ws[OFF_H1P + inp * 256 + l32 * 8 + j]);
    f32x8 acc = {0.f, 0.f, 0.f, 0.f, 0.f, 0.f, 0.f, 0.f};
    int wid = bl * 4 + w;
    int base = wid * 2;
    for (; base + 1 < N; base += 4096) {
        int row = base + half;
        f32x8 v = ld8(x, (size_t)row * 32 + l32);
        float d = dot8(v, h1);
#pragma unroll
        for (int off = 16; off; off >>= 1) d += __shfl_xor(d, off, 64);  // 32-lane half
        acc += sigmoidf_(d) * v;
    }
    if (base < N && half == 0) {           // odd-N tail (dead for even N)
        f32x8 v = ld8(x, (size_t)base * 32 + l32);
        float d = dot8(v, h1);
#pragma unroll
        for (int off = 16; off; off >>= 1) d += __shfl_xor(d, off, 64);
        acc += sigmoidf_(d) * v;
    }
    block_reduce_store8(acc, t, ws + OFF_PARTB + ((size_t)inp * 512 + bl) * 256);
}

// Pass C: o = sum_i att1_i*att2_i*x_i, att2_i = sigmoid(att1_i * (x_i . h2)).
template<typename T>
__global__ void k_att2_t(const T* __restrict__ b1, const T* __restrict__ b2,
                         int N1, int N2, float* __restrict__ ws) {
    int b = blockIdx.x, t = threadIdx.x;
    int inp = (b < 512) ? 0 : 1;
    int bl = inp ? (b - 512) : b;
    const T* x = inp ? b2 : b1;
    int N = inp ? N2 : N1;
    int lane = t & 63, w = t >> 6;
    int half = lane >> 5, l32 = lane & 31;
    f32x8 h1, h2;
#pragma unroll
    for (int j = 0; j < 8; j++) {
        h1[j] = tanhf(ws[OFF_H1P + inp * 256 + l32 * 8 + j]);
        h2[j] = tanhf(ws[OFF_H2P + inp * 256 + l32 * 8 + j]);
    }
    f32x8 acc = {0.f, 0.f, 0.f, 0.f, 0.f, 0.f, 0.f, 0.f};
    int wid = bl * 4 + w;
    int base = wid * 2;
    for (; base + 1 < N; base += 4096) {
        int row = base + half;
        f32x8 v = ld8(x, (size_t)row * 32 + l32);
        float d = dot8(v, h1), e = dot8(v, h2);
#pragma unroll
        for (int off = 16; off; off >>= 1) {
            d += __shfl_xor(d, off, 64); e += __shfl_xor(e, off, 64);
        }
        float a1 = sigmoidf_(d);
        acc += (a1 * sigmoidf_(a1 * e)) * v;
    }
    if (base < N && half == 0) {
        f32x8 v = ld8(x, (size_t)base * 32 + l32);
        float d = dot8(v, h1), e = dot8(v, h2);
#pragma unroll
        for (int off = 16; off; off >>= 1) {
            d += __shfl_xor(d, off, 64); e += __shfl_xor(e, off, 64);
        }
        float a1 = sigmoidf_(d);
        acc += (a1 * sigmoidf_(a1 * e)) * v;
    }
    block_reduce_store8(acc, t, ws + OFF_PARTO + ((size_t)inp * 512 + bl) * 256);
}

// w_term partials: g1.W[f].g2 with g=[o,o] folded. Each block PLAIN-STORES its
// 16 values to PWT[b][w*4+u]; k_final reduces them (no global atomics).
__global__ void __launch_bounds__(256, 4)
k_ntn(const float* __restrict__ W, float* __restrict__ ws) {
    __shared__ __align__(16) float o_l[512];
    int b = blockIdx.x, t = threadIdx.x;
    o_l[t] = ws[OFF_O + t];
    o_l[256 + t] = ws[OFF_O + 256 + t];
    __syncthreads();
    int lane = t & 63, w = t >> 6;
    f32x4 o2f = ((const f32x4*)(o_l + 256))[lane];
    int g = b * 4 + w;              // global wave id, 2048 waves
    const f32x4* W4 = (const f32x4*)W;
    float wt[4];
#pragma unroll
    for (int u = 0; u < 4; u++) {
        int row = g + u * 2048;     // (f,d) flat, 8192 rows
        const f32x4* q = W4 + (size_t)row * 128 + lane;
        f32x4 m = (q[0] + q[64]) * o2f;
        float p = (m.x + m.y) + (m.z + m.w);
#pragma unroll
        for (int off = 32; off; off >>= 1) p += __shfl_xor(p, off, 64);
        wt[u] = o_l[row & 255] * p;
    }
    if (lane == 0) {
#pragma unroll
        for (int u = 0; u < 4; u++) ws[OFF_PWT + b * 16 + w * 4 + u] = wt[u];
    }
}

// v_term + w_term + b -> sigmoid -> 4-layer MLP -> out[0].
__global__ void k_final(const float* __restrict__ V, const float* __restrict__ bb,
                        const float* __restrict__ P0, const float* __restrict__ P1,
                        const float* __restrict__ P2, const float* __restrict__ P3,
                        float* __restrict__ ws, float* __restrict__ out) {
    int t = threadIdx.x;           // 256 threads
    __shared__ float o_l[512];
    o_l[t] = ws[OFF_O + t];
    o_l[256 + t] = ws[OFF_O + 256 + t];
    __shared__ float wtl[16];
    if (t < 16) wtl[t] = 0.f;
    __syncthreads();
    // reduce ntn partials: entry i=(b,w,u) -> f = (b*4 + w + u*2048) >> 9
    for (int i = t; i < 8192; i += 256) {
        int b = i >> 4, w = (i >> 2) & 3, u = i & 3;
        int f = (b * 4 + w + u * 2048) >> 9;
        atomicAdd(&wtl[f], ws[OFF_PWT + i]);        // LDS atomic (cheap)
    }
    int f = t >> 4, j = t & 15;
    float p = 0.f;
    for (int k = j; k < 1024; k += 16) {
        float cv = (k < 512) ? o_l[k & 255] : o_l[256 + (k & 255)];
        p += cv * V[f * 1024 + k];
    }
    __shared__ float red[256];
    __shared__ float sv[16];
    red[t] = p;
    __syncthreads();
    if (t < 16) {
        float v = 0.f;
#pragma unroll
        for (int q = 0; q < 16; q++) v += red[t * 16 + q];
        sv[t] = sigmoidf_(v + wtl[t] + bb[t]);
    }
    __syncthreads();
    if (t == 0) {
        float y0[8], y1[4], y2[2];
#pragma unroll
        for (int i = 0; i < 8; i++) {
            float s = 0.f;
            for (int k = 0; k < 16; k++) s += P0[i * 16 + k] * sv[k];
            y0[i] = sigmoidf_(s);
        }
#pragma unroll
        for (int i = 0; i < 4; i++) {
            float s = 0.f;
            for (int k = 0; k < 8; k++) s += P1[i * 8 + k] * y0[k];
            y1[i] = sigmoidf_(s);
        }
#pragma unroll
        for (int i = 0; i < 2; i++) {
            float s = 0.f;
            for (int k = 0; k < 4; k++) s += P2[i * 4 + k] * y1[k];
            y2[i] = sigmoidf_(s);
        }
        out[0] = sigmoidf_(P3[0] * y2[0] + P3[1] * y2[1]);
    }
}

extern "C" void kernel_launch(void* const* d_in, const int* in_sizes, int n_in,
                              void* d_out, int out_size, void* d_ws, size_t ws_size,
                              hipStream_t stream) {
    const float* x1 = (const float*)d_in[0];
    const float* x2 = (const float*)d_in[1];
    const float* W0 = (const float*)d_in[2];
    const float* V  = (const float*)d_in[3];
    const float* W  = (const float*)d_in[4];
    const float* b  = (const float*)d_in[5];
    const float* P0 = (const float*)d_in[6];
    const float* P1 = (const float*)d_in[7];
    const float* P2 = (const float*)d_in[8];
    const float* P3 = (const float*)d_in[9];
    float* ws  = (float*)d_ws;
    float* out = (float*)d_out;
    int N1 = in_sizes[0] / DD;   // 120000
    int N2 = in_sizes[1] / DD;   // 100000

    const f32x4* x1v = (const f32x4*)x1;
    const f32x4* x2v = (const f32x4*)x2;
    f16x4* m1 = (f16x4*)((char*)d_ws + MIRROR_OFF_BYTES);
    f16x4* m2 = m1 + (size_t)N1 * 64;
    size_t need = (size_t)MIRROR_OFF_BYTES + ((size_t)N1 + N2) * DD * sizeof(_Float16);
    bool use_mirror = ws_size >= need;

    if (use_mirror) {
        k_mean_t<true>  <<<1024, 256, 0, stream>>>(x1v, x2v, m1, m2, N1, N2, ws);
        k_h             <<<2,   1024, 0, stream>>>(W0, ws, OFF_PARTA, OFF_H1P, N1, N2);
        k_att1_t<f16x8> <<<1024, 256, 0, stream>>>((const f16x8*)m1, (const f16x8*)m2, N1, N2, ws);
        k_h             <<<2,   1024, 0, stream>>>(W0, ws, OFF_PARTB, OFF_H2P, N1, N2);
        k_att2_t<f16x8> <<<1024, 256, 0, stream>>>((const f16x8*)m1, (const f16x8*)m2, N1, N2, ws);
    } else {
        k_mean_t<false> <<<1024, 256, 0, stream>>>(x1v, x2v, nullptr, nullptr, N1, N2, ws);
        k_h             <<<2,   1024, 0, stream>>>(W0, ws, OFF_PARTA, OFF_H1P, N1, N2);
        k_att1_t<f32x8> <<<1024, 256, 0, stream>>>((const f32x8*)x1, (const f32x8*)x2, N1, N2, ws);
        k_h             <<<2,   1024, 0, stream>>>(W0, ws, OFF_PARTB, OFF_H2P, N1, N2);
        k_att2_t<f32x8> <<<1024, 256, 0, stream>>>((const f32x8*)x1, (const f32x8*)x2, N1, N2, ws);
    }
    k_redo <<<2,  1024, 0, stream>>>(ws);
    k_ntn  <<<512, 256, 0, stream>>>(W, ws);
    k_final<<<1,   256, 0, stream>>>(V, b, P0, P1, P2, P3, ws, out);
}